// Round 2
// baseline (345.953 us; speedup 1.0000x reference)
//
#include <hip/hip_runtime.h>
#include <hip/hip_bf16.h>
#include <hip/hip_fp16.h>
#include <stdint.h>

// ---------------------------------------------------------------------------
// AttentionLayer: Q=XWq+bq, K=XWk+bk, V=XWv+bv; O = softmax(QK^T) V
// B=4, N=2048, D_IN=D_OUT=1024. Device tensors are fp32 (reference dtype).
// Internals: X,W,Q,K,V,P in fp16 (MFMA inputs); S and all accumulation fp32.
// ---------------------------------------------------------------------------

typedef unsigned short ushort_t;
typedef __attribute__((ext_vector_type(8))) _Float16  f16x8;
typedef __attribute__((ext_vector_type(4))) float     f32x4;

__device__ __forceinline__ void store_out(float* p, float v) { *p = v; }
__device__ __forceinline__ void store_out(__half* p, float v) { *p = __float2half(v); }

__device__ __forceinline__ void async_load16(const void* g, void* l) {
  __builtin_amdgcn_global_load_lds(
      (const __attribute__((address_space(1))) void*)g,
      (__attribute__((address_space(3))) void*)l, 16, 0, 0);
}

// ---------------------------------------------------------------------------
// C[m][n] = sum_k A[m][k] * BT[n][k]  (+ bias[n]); fp32 accumulate.
// A,BT fp16. 128x128 tile, BK=32, 256 thr = 4 waves (2x2), 4x4 MFMA each.
// Batched via blockIdx.z. m97-style global_load_lds width-16 staging.
// ---------------------------------------------------------------------------
template <typename OutT, bool HAS_BIAS>
__global__ __launch_bounds__(256)
void gemm_bt_kernel(const ushort_t* __restrict__ A, const ushort_t* __restrict__ BT,
                    const float* __restrict__ bias, OutT* __restrict__ C,
                    int M, int N, int K,
                    long batchA, long batchB, long batchC)
{
  __shared__ ushort_t As[128 * 32];
  __shared__ ushort_t Bs[128 * 32];

  const int t    = threadIdx.x;
  const int lane = t & 63;
  const int wave = t >> 6;
  const int wm   = (wave >> 1) * 64;  // wave row origin in tile
  const int wn   = (wave & 1) * 64;   // wave col origin in tile

  const ushort_t* Ab = A + (long)blockIdx.z * batchA + (long)blockIdx.y * 128 * K;
  const ushort_t* Bb = BT + (long)blockIdx.z * batchB + (long)blockIdx.x * 128 * K;
  OutT* Cb = C + (long)blockIdx.z * batchC;

  // staging: 256 thr x 16B = 4KB = 64 rows x 32 cols fp16; 2 issues per array
  const int ldr = t >> 2;          // row 0..63 within issue group
  const int ldc = (t & 3) * 8;     // col chunk (8 elems = 16B)
  // fragment coords (16x16x32: lane holds [m=lane&15][k=(lane>>4)*8 + j])
  const int frow = lane & 15;
  const int fk   = (lane >> 4) * 8;

  f32x4 acc[4][4];
  const f32x4 zero = {0.0f, 0.0f, 0.0f, 0.0f};
#pragma unroll
  for (int i = 0; i < 4; ++i)
#pragma unroll
    for (int j = 0; j < 4; ++j) acc[i][j] = zero;

  for (int k0 = 0; k0 < K; k0 += 32) {
    __syncthreads();  // previous tile's compute done before LDS overwrite
    const ushort_t* ga = Ab + (long)ldr * K + k0 + ldc;
    const ushort_t* gb = Bb + (long)ldr * K + k0 + ldc;
    async_load16(ga,                &As[t * 8]);
    async_load16(ga + 64 * (long)K, &As[2048 + t * 8]);
    async_load16(gb,                &Bs[t * 8]);
    async_load16(gb + 64 * (long)K, &Bs[2048 + t * 8]);
    __syncthreads();  // barrier drains vmcnt -> LDS ready

    f16x8 af[4], bf[4];
#pragma unroll
    for (int i = 0; i < 4; ++i) {
      af[i] = *(const f16x8*)&As[(wm + i * 16 + frow) * 32 + fk];
      bf[i] = *(const f16x8*)&Bs[(wn + i * 16 + frow) * 32 + fk];
    }
#pragma unroll
    for (int mi = 0; mi < 4; ++mi)
#pragma unroll
      for (int ni = 0; ni < 4; ++ni)
        acc[mi][ni] = __builtin_amdgcn_mfma_f32_16x16x32_f16(af[mi], bf[ni], acc[mi][ni], 0, 0, 0);
  }

  // C/D layout (m89-verified): col = lane&15, row = (lane>>4)*4 + reg
  const int er = (lane >> 4) * 4;
  const int ec = lane & 15;
#pragma unroll
  for (int ni = 0; ni < 4; ++ni) {
    const int gcol = blockIdx.x * 128 + wn + ni * 16 + ec;
    float bv = 0.0f;
    if (HAS_BIAS) bv = bias[gcol];
#pragma unroll
    for (int mi = 0; mi < 4; ++mi) {
#pragma unroll
      for (int r = 0; r < 4; ++r) {
        const long grow = (long)blockIdx.y * 128 + wm + mi * 16 + er + r;
        store_out(&Cb[grow * (long)N + gcol], acc[mi][ni][r] + bv);
      }
    }
  }
}

// ---------------------------------------------------------------------------
// fp32 -> fp16 elementwise convert, 8 elems/thread, 16B stores.
// ---------------------------------------------------------------------------
__global__ __launch_bounds__(256)
void cvt_f32_f16_kernel(const float* __restrict__ src, __half* __restrict__ dst, long n)
{
  const long i = ((long)blockIdx.x * 256 + threadIdx.x) * 8;
  if (i + 8 > n) return;
  const float4 a = *(const float4*)(src + i);
  const float4 b = *(const float4*)(src + i + 4);
  f16x8 h;
  h[0] = (_Float16)a.x; h[1] = (_Float16)a.y; h[2] = (_Float16)a.z; h[3] = (_Float16)a.w;
  h[4] = (_Float16)b.x; h[5] = (_Float16)b.y; h[6] = (_Float16)b.z; h[7] = (_Float16)b.w;
  *(f16x8*)((ushort_t*)dst + i) = h;
}

// ---------------------------------------------------------------------------
// fp32 [R][C] -> transposed fp16 [C][R]. 32x32 LDS tile (+1 pad), 256 thr.
// ---------------------------------------------------------------------------
__global__ __launch_bounds__(256)
void transpose_cvt_kernel(const float* __restrict__ src, __half* __restrict__ dst,
                          int R, int Cc)
{
  __shared__ float tile[32][33];
  const int c0 = blockIdx.x * 32;
  const int r0 = blockIdx.y * 32;
  const int tx = threadIdx.x & 31;
  const int ty = threadIdx.x >> 5;  // 0..7
#pragma unroll
  for (int i = 0; i < 32; i += 8)
    tile[ty + i][tx] = src[(long)(r0 + ty + i) * Cc + (c0 + tx)];
  __syncthreads();
#pragma unroll
  for (int i = 0; i < 32; i += 8)
    dst[(long)(c0 + ty + i) * R + (r0 + tx)] = __float2half(tile[tx][ty + i]);
}

// ---------------------------------------------------------------------------
// fp16 [R][C] -> fp16 [C][R] (batched). 32x32 LDS tile (+1 pad), 256 thr.
// ---------------------------------------------------------------------------
__global__ __launch_bounds__(256)
void transpose2b_kernel(const ushort_t* __restrict__ src, ushort_t* __restrict__ dst,
                        int R, int Cc, long sStride, long dStride)
{
  __shared__ ushort_t tile[32][33];
  const int c0 = blockIdx.x * 32;
  const int r0 = blockIdx.y * 32;
  const int tx = threadIdx.x & 31;
  const int ty = threadIdx.x >> 5;
  const ushort_t* s = src + (long)blockIdx.z * sStride;
  ushort_t* d = dst + (long)blockIdx.z * dStride;
#pragma unroll
  for (int i = 0; i < 32; i += 8)
    tile[ty + i][tx] = s[(long)(r0 + ty + i) * Cc + (c0 + tx)];
  __syncthreads();
#pragma unroll
  for (int i = 0; i < 32; i += 8)
    d[(long)(c0 + ty + i) * R + (r0 + tx)] = tile[tx][ty + i];
}

// ---------------------------------------------------------------------------
// Row softmax over 2048 fp32 cols -> fp16. One 256-thread block per row.
// ---------------------------------------------------------------------------
__global__ __launch_bounds__(256)
void softmax2048_kernel(const float* __restrict__ S, __half* __restrict__ P)
{
  const long row = blockIdx.x;
  const float* s = S + row * 2048;
  const int t = threadIdx.x;

  const float4 a = ((const float4*)s)[t * 2];
  const float4 b = ((const float4*)s)[t * 2 + 1];
  float v[8] = {a.x, a.y, a.z, a.w, b.x, b.y, b.z, b.w};

  float mx = v[0];
#pragma unroll
  for (int i = 1; i < 8; ++i) mx = fmaxf(mx, v[i]);
#pragma unroll
  for (int off = 32; off > 0; off >>= 1) mx = fmaxf(mx, __shfl_xor(mx, off, 64));

  __shared__ float redm[4], reds[4];
  if ((t & 63) == 0) redm[t >> 6] = mx;
  __syncthreads();
  mx = fmaxf(fmaxf(redm[0], redm[1]), fmaxf(redm[2], redm[3]));

  float sum = 0.0f;
#pragma unroll
  for (int i = 0; i < 8; ++i) { v[i] = __expf(v[i] - mx); sum += v[i]; }
#pragma unroll
  for (int off = 32; off > 0; off >>= 1) sum += __shfl_xor(sum, off, 64);
  if ((t & 63) == 0) reds[t >> 6] = sum;
  __syncthreads();
  sum = reds[0] + reds[1] + reds[2] + reds[3];

  const float inv = 1.0f / sum;
  f16x8 h;
#pragma unroll
  for (int i = 0; i < 8; ++i) h[i] = (_Float16)(v[i] * inv);
  *(f16x8*)((ushort_t*)P + row * 2048 + t * 8) = h;  // 16B coalesced store
}

// ---------------------------------------------------------------------------
extern "C" void kernel_launch(void* const* d_in, const int* in_sizes, int n_in,
                              void* d_out, int out_size, void* d_ws, size_t ws_size,
                              hipStream_t stream)
{
  const int  Bb = 4, Nn = 2048, Dd = 1024;
  const long BN = (long)Bb * Nn;  // 8192

  const float* X  = (const float*)d_in[0];
  const float* Wq = (const float*)d_in[1];
  const float* bq = (const float*)d_in[2];
  const float* Wk = (const float*)d_in[3];
  const float* bk = (const float*)d_in[4];
  const float* Wv = (const float*)d_in[5];
  const float* bv = (const float*)d_in[6];
  float* Out      = (float*)d_out;

  uint8_t* w = (uint8_t*)d_ws;
  ushort_t* Wt = (ushort_t*)w;  w += (size_t)3 * Dd * Dd * 2;  // W^T x3, fp16

  // Wt[e][k] = W[k][e], fp32 -> fp16
  transpose_cvt_kernel<<<dim3(Dd / 32, Dd / 32, 1), 256, 0, stream>>>(Wq, (__half*)Wt,               Dd, Dd);
  transpose_cvt_kernel<<<dim3(Dd / 32, Dd / 32, 1), 256, 0, stream>>>(Wk, (__half*)(Wt + Dd * Dd),   Dd, Dd);
  transpose_cvt_kernel<<<dim3(Dd / 32, Dd / 32, 1), 256, 0, stream>>>(Wv, (__half*)(Wt + 2 * Dd * Dd), Dd, Dd);

  const size_t fullNeed = (size_t)3 * Dd * Dd * 2      // Wt
                        + (size_t)BN * Dd * 2          // Xh
                        + 4 * ((size_t)BN * Dd * 2)    // Q,K,V,Vt fp16
                        + (size_t)Bb * Nn * Nn * 4     // S fp32
                        + (size_t)Bb * Nn * Nn * 2;    // P fp16

  if (ws_size >= fullNeed) {
    ushort_t* Xh = (ushort_t*)w;  w += (size_t)BN * Dd * 2;
    ushort_t* Q  = (ushort_t*)w;  w += (size_t)BN * Dd * 2;
    ushort_t* Kb = (ushort_t*)w;  w += (size_t)BN * Dd * 2;
    ushort_t* Vb = (ushort_t*)w;  w += (size_t)BN * Dd * 2;
    ushort_t* Vt = (ushort_t*)w;  w += (size_t)BN * Dd * 2;  // [B][Dd][Nn]
    float*    S  = (float*)w;     w += (size_t)Bb * Nn * Nn * 4;
    ushort_t* P  = (ushort_t*)w;

    // X -> fp16
    cvt_f32_f16_kernel<<<dim3((unsigned)(BN * Dd / (8 * 256))), 256, 0, stream>>>(
        X, (__half*)Xh, BN * Dd);

    // QKV projections: [8192,1024] x Wt (+bias) -> fp16
    gemm_bt_kernel<__half, true><<<dim3(Dd / 128, BN / 128, 1), 256, 0, stream>>>(
        Xh, Wt,               bq, (__half*)Q,  (int)BN, Dd, Dd, 0, 0, 0);
    gemm_bt_kernel<__half, true><<<dim3(Dd / 128, BN / 128, 1), 256, 0, stream>>>(
        Xh, Wt + Dd * Dd,     bk, (__half*)Kb, (int)BN, Dd, Dd, 0, 0, 0);
    gemm_bt_kernel<__half, true><<<dim3(Dd / 128, BN / 128, 1), 256, 0, stream>>>(
        Xh, Wt + 2 * Dd * Dd, bv, (__half*)Vb, (int)BN, Dd, Dd, 0, 0, 0);

    // V^T per batch: Vt[b][e][m] = V[b][m][e]
    transpose2b_kernel<<<dim3(Dd / 32, Nn / 32, Bb), 256, 0, stream>>>(
        Vb, Vt, Nn, Dd, (long)Nn * Dd, (long)Dd * Nn);

    // S[b] = Q[b] K[b]^T  (fp32)
    gemm_bt_kernel<float, false><<<dim3(Nn / 128, Nn / 128, Bb), 256, 0, stream>>>(
        Q, Kb, nullptr, S, Nn, Nn, Dd, (long)Nn * Dd, (long)Nn * Dd, (long)Nn * Nn);

    // P = softmax(S) rows -> fp16
    softmax2048_kernel<<<dim3((unsigned)(Bb * (long)Nn)), 256, 0, stream>>>(S, (__half*)P);

    // O[b] = P[b] V[b]  via Vt -> fp32 out
    gemm_bt_kernel<float, false><<<dim3(Dd / 128, Nn / 128, Bb), 256, 0, stream>>>(
        P, Vt, nullptr, Out, Nn, Dd, Nn, (long)Nn * Nn, (long)Dd * Nn, (long)Nn * Dd);
  } else {
    // Per-batch fallback (~53 MB ws)
    ushort_t* Xh = (ushort_t*)w;  w += (size_t)Nn * Dd * 2;
    ushort_t* Q  = (ushort_t*)w;  w += (size_t)Nn * Dd * 2;
    ushort_t* Kb = (ushort_t*)w;  w += (size_t)Nn * Dd * 2;
    ushort_t* Vb = (ushort_t*)w;  w += (size_t)Nn * Dd * 2;
    ushort_t* Vt = (ushort_t*)w;  w += (size_t)Nn * Dd * 2;
    float*    S  = (float*)w;     w += (size_t)Nn * Nn * 4;
    ushort_t* P  = (ushort_t*)w;

    for (int b = 0; b < Bb; ++b) {
      const float* Xb = X + (long)b * Nn * Dd;
      cvt_f32_f16_kernel<<<dim3((unsigned)((long)Nn * Dd / (8 * 256))), 256, 0, stream>>>(
          Xb, (__half*)Xh, (long)Nn * Dd);
      gemm_bt_kernel<__half, true><<<dim3(Dd / 128, Nn / 128, 1), 256, 0, stream>>>(
          Xh, Wt,               bq, (__half*)Q,  Nn, Dd, Dd, 0, 0, 0);
      gemm_bt_kernel<__half, true><<<dim3(Dd / 128, Nn / 128, 1), 256, 0, stream>>>(
          Xh, Wt + Dd * Dd,     bk, (__half*)Kb, Nn, Dd, Dd, 0, 0, 0);
      gemm_bt_kernel<__half, true><<<dim3(Dd / 128, Nn / 128, 1), 256, 0, stream>>>(
          Xh, Wt + 2 * Dd * Dd, bv, (__half*)Vb, Nn, Dd, Dd, 0, 0, 0);
      transpose2b_kernel<<<dim3(Dd / 32, Nn / 32, 1), 256, 0, stream>>>(
          Vb, Vt, Nn, Dd, 0, 0);
      gemm_bt_kernel<float, false><<<dim3(Nn / 128, Nn / 128, 1), 256, 0, stream>>>(
          Q, Kb, nullptr, S, Nn, Nn, Dd, 0, 0, 0);
      softmax2048_kernel<<<dim3(Nn), 256, 0, stream>>>(S, (__half*)P);
      gemm_bt_kernel<float, false><<<dim3(Dd / 128, Nn / 128, 1), 256, 0, stream>>>(
          P, Vt, nullptr, Out + (long)b * Nn * Dd, Nn, Dd, Nn, 0, 0, 0);
    }
  }
}

// Round 3
// 287.944 us; speedup vs baseline: 1.2015x; 1.2015x over previous
//
#include <hip/hip_runtime.h>
#include <hip/hip_bf16.h>
#include <hip/hip_fp16.h>
#include <stdint.h>

// ---------------------------------------------------------------------------
// AttentionLayer: Q=XWq+bq, K=XWk+bk, V=XWv+bv; O = softmax(QK^T) V
// B=4, N=2048, D=1024. fp32 I/O; internals fp16 (MFMA), S + accum fp32.
// R3: fused QKV GEMM (V written pre-transposed), 2 K-steps per barrier pair.
// ---------------------------------------------------------------------------

typedef unsigned short ushort_t;
typedef __attribute__((ext_vector_type(8))) _Float16  f16x8;
typedef __attribute__((ext_vector_type(4))) _Float16  f16x4;
typedef __attribute__((ext_vector_type(4))) float     f32x4;

__device__ __forceinline__ void store_out(float* p, float v) { *p = v; }
__device__ __forceinline__ void store_out(__half* p, float v) { *p = __float2half(v); }

__device__ __forceinline__ void async_load16(const void* g, void* l) {
  __builtin_amdgcn_global_load_lds(
      (const __attribute__((address_space(1))) void*)g,
      (__attribute__((address_space(3))) void*)l, 16, 0, 0);
}

// ---------------------------------------------------------------------------
// Generic C[m][n] = sum_k A[m][k]*BT[n][k], fp16 in, fp32 acc. 128x128 tile.
// K-loop does 2 BK=32 steps per barrier pair (paired 8KB LDS buffers keep the
// proven BK=32 bank layout; 32KB LDS total -> 5 blocks/CU). K % 64 == 0.
// ---------------------------------------------------------------------------
template <typename OutT>
__global__ __launch_bounds__(256)
void gemm_bt_kernel(const ushort_t* __restrict__ A, const ushort_t* __restrict__ BT,
                    OutT* __restrict__ C, int N, int K,
                    long batchA, long batchB, long batchC)
{
  __shared__ ushort_t As[2][128 * 32];
  __shared__ ushort_t Bs[2][128 * 32];

  const int t    = threadIdx.x;
  const int lane = t & 63;
  const int wave = t >> 6;
  const int wm   = (wave >> 1) * 64;
  const int wn   = (wave & 1) * 64;

  const ushort_t* Ab = A + (long)blockIdx.z * batchA + (long)blockIdx.y * 128 * K;
  const ushort_t* Bb = BT + (long)blockIdx.z * batchB + (long)blockIdx.x * 128 * K;
  OutT* Cb = C + (long)blockIdx.z * batchC;

  const int ldr = t >> 2;          // 0..63
  const int ldc = (t & 3) * 8;     // 16B col chunk
  const int frow = lane & 15;
  const int fo   = (lane >> 4) * 8;

  f32x4 acc[4][4];
  const f32x4 zero = {0.0f, 0.0f, 0.0f, 0.0f};
#pragma unroll
  for (int i = 0; i < 4; ++i)
#pragma unroll
    for (int j = 0; j < 4; ++j) acc[i][j] = zero;

  for (int k0 = 0; k0 < K; k0 += 64) {
    __syncthreads();
    const ushort_t* ga = Ab + (long)ldr * K + k0 + ldc;
    const ushort_t* gb = Bb + (long)ldr * K + k0 + ldc;
#pragma unroll
    for (int h = 0; h < 2; ++h) {
      async_load16(ga + h * 32,                &As[h][t * 8]);
      async_load16(ga + h * 32 + 64 * (long)K, &As[h][2048 + t * 8]);
      async_load16(gb + h * 32,                &Bs[h][t * 8]);
      async_load16(gb + h * 32 + 64 * (long)K, &Bs[h][2048 + t * 8]);
    }
    __syncthreads();
#pragma unroll
    for (int h = 0; h < 2; ++h) {
      f16x8 af[4], bf[4];
#pragma unroll
      for (int i = 0; i < 4; ++i) {
        af[i] = *(const f16x8*)&As[h][(wm + i * 16 + frow) * 32 + fo];
        bf[i] = *(const f16x8*)&Bs[h][(wn + i * 16 + frow) * 32 + fo];
      }
#pragma unroll
      for (int mi = 0; mi < 4; ++mi)
#pragma unroll
        for (int ni = 0; ni < 4; ++ni)
          acc[mi][ni] = __builtin_amdgcn_mfma_f32_16x16x32_f16(af[mi], bf[ni], acc[mi][ni], 0, 0, 0);
    }
  }

  // C/D layout: col = lane&15, row = (lane>>4)*4 + reg
  const int er = (lane >> 4) * 4;
  const int ec = lane & 15;
#pragma unroll
  for (int ni = 0; ni < 4; ++ni) {
    const int gcol = blockIdx.x * 128 + wn + ni * 16 + ec;
#pragma unroll
    for (int mi = 0; mi < 4; ++mi) {
#pragma unroll
      for (int r = 0; r < 4; ++r) {
        const long grow = (long)blockIdx.y * 128 + wm + mi * 16 + er + r;
        store_out(&Cb[grow * (long)N + gcol], acc[mi][ni][r]);
      }
    }
  }
}

// ---------------------------------------------------------------------------
// Fused QKV projection: A = Xh [M][1024], BT = WtAll [3072][1024] (Wq|Wk|Wv).
// blockIdx.x in [0,24): tgt = x>>3 selects Q / K / V-transposed output.
// Q,K stored [M][1024] fp16; V stored transposed Vt[b][e][m] (b = grow>>11).
// ---------------------------------------------------------------------------
__global__ __launch_bounds__(256)
void qkv_gemm_kernel(const ushort_t* __restrict__ A, const ushort_t* __restrict__ BT,
                     const float* __restrict__ bq, const float* __restrict__ bk,
                     const float* __restrict__ bvp,
                     __half* __restrict__ Qh, __half* __restrict__ Kh,
                     ushort_t* __restrict__ Vt)
{
  const int K = 1024;
  __shared__ ushort_t As[2][128 * 32];
  __shared__ ushort_t Bs[2][128 * 32];

  const int t    = threadIdx.x;
  const int lane = t & 63;
  const int wave = t >> 6;
  const int wm   = (wave >> 1) * 64;
  const int wn   = (wave & 1) * 64;

  const ushort_t* Ab = A + (long)blockIdx.y * 128 * K;
  const ushort_t* Bb = BT + (long)blockIdx.x * 128 * K;

  const int ldr = t >> 2;
  const int ldc = (t & 3) * 8;
  const int frow = lane & 15;
  const int fo   = (lane >> 4) * 8;

  f32x4 acc[4][4];
  const f32x4 zero = {0.0f, 0.0f, 0.0f, 0.0f};
#pragma unroll
  for (int i = 0; i < 4; ++i)
#pragma unroll
    for (int j = 0; j < 4; ++j) acc[i][j] = zero;

  for (int k0 = 0; k0 < K; k0 += 64) {
    __syncthreads();
    const ushort_t* ga = Ab + (long)ldr * K + k0 + ldc;
    const ushort_t* gb = Bb + (long)ldr * K + k0 + ldc;
#pragma unroll
    for (int h = 0; h < 2; ++h) {
      async_load16(ga + h * 32,                &As[h][t * 8]);
      async_load16(ga + h * 32 + 64 * (long)K, &As[h][2048 + t * 8]);
      async_load16(gb + h * 32,                &Bs[h][t * 8]);
      async_load16(gb + h * 32 + 64 * (long)K, &Bs[h][2048 + t * 8]);
    }
    __syncthreads();
#pragma unroll
    for (int h = 0; h < 2; ++h) {
      f16x8 af[4], bf[4];
#pragma unroll
      for (int i = 0; i < 4; ++i) {
        af[i] = *(const f16x8*)&As[h][(wm + i * 16 + frow) * 32 + fo];
        bf[i] = *(const f16x8*)&Bs[h][(wn + i * 16 + frow) * 32 + fo];
      }
#pragma unroll
      for (int mi = 0; mi < 4; ++mi)
#pragma unroll
        for (int ni = 0; ni < 4; ++ni)
          acc[mi][ni] = __builtin_amdgcn_mfma_f32_16x16x32_f16(af[mi], bf[ni], acc[mi][ni], 0, 0, 0);
    }
  }

  const int er = (lane >> 4) * 4;
  const int ec = lane & 15;
  const int tgt = blockIdx.x >> 3;  // 0:Q 1:K 2:V (128 | 1024, so block-uniform)
  const float* bias = (tgt == 0) ? bq : (tgt == 1) ? bk : bvp;
#pragma unroll
  for (int ni = 0; ni < 4; ++ni) {
    const int c = (blockIdx.x & 7) * 128 + wn + ni * 16 + ec;  // 0..1023
    const float bval = bias[c];
#pragma unroll
    for (int mi = 0; mi < 4; ++mi) {
      const long grow0 = (long)blockIdx.y * 128 + wm + mi * 16 + er;
      if (tgt < 2) {
        __half* o = (tgt == 0) ? Qh : Kh;
#pragma unroll
        for (int r = 0; r < 4; ++r)
          o[(grow0 + r) * 1024 + c] = __float2half(acc[mi][ni][r] + bval);
      } else {
        const long b  = grow0 >> 11;       // batch (N=2048 rows per batch)
        const long ml = grow0 & 2047;      // aligned to 4
        f16x4 v4;
#pragma unroll
        for (int r = 0; r < 4; ++r) v4[r] = (_Float16)(acc[mi][ni][r] + bval);
        *(f16x4*)&Vt[b * 2097152 + (long)c * 2048 + ml] = v4;  // 8B store
      }
    }
  }
}

// ---------------------------------------------------------------------------
// fp32 -> fp16 elementwise, 8 elems/thread, 16B stores.
// ---------------------------------------------------------------------------
__global__ __launch_bounds__(256)
void cvt_f32_f16_kernel(const float* __restrict__ src, __half* __restrict__ dst, long n)
{
  const long i = ((long)blockIdx.x * 256 + threadIdx.x) * 8;
  if (i + 8 > n) return;
  const float4 a = *(const float4*)(src + i);
  const float4 b = *(const float4*)(src + i + 4);
  f16x8 h;
  h[0] = (_Float16)a.x; h[1] = (_Float16)a.y; h[2] = (_Float16)a.z; h[3] = (_Float16)a.w;
  h[4] = (_Float16)b.x; h[5] = (_Float16)b.y; h[6] = (_Float16)b.z; h[7] = (_Float16)b.w;
  *(f16x8*)((ushort_t*)dst + i) = h;
}

// ---------------------------------------------------------------------------
// Batched weight transpose+convert: dst[z][c][r] = (fp16)srcz[r][c], 1024x1024.
// z selects Wq/Wk/Wv source pointer.
// ---------------------------------------------------------------------------
__global__ __launch_bounds__(256)
void transpose_cvt3_kernel(const float* __restrict__ W0, const float* __restrict__ W1,
                           const float* __restrict__ W2, __half* __restrict__ dst)
{
  __shared__ float tile[32][33];
  const int z = blockIdx.z;
  const float* src = (z == 0) ? W0 : (z == 1) ? W1 : W2;
  __half* d = dst + (long)z * 1024 * 1024;
  const int c0 = blockIdx.x * 32;
  const int r0 = blockIdx.y * 32;
  const int tx = threadIdx.x & 31;
  const int ty = threadIdx.x >> 5;
#pragma unroll
  for (int i = 0; i < 32; i += 8)
    tile[ty + i][tx] = src[(long)(r0 + ty + i) * 1024 + (c0 + tx)];
  __syncthreads();
#pragma unroll
  for (int i = 0; i < 32; i += 8)
    d[(long)(c0 + ty + i) * 1024 + (r0 + tx)] = __float2half(tile[tx][ty + i]);
}

// ---------------------------------------------------------------------------
// Row softmax over 2048 fp32 cols -> fp16. One 256-thread block per row.
// ---------------------------------------------------------------------------
__global__ __launch_bounds__(256)
void softmax2048_kernel(const float* __restrict__ S, __half* __restrict__ P)
{
  const long row = blockIdx.x;
  const float* s = S + row * 2048;
  const int t = threadIdx.x;

  const float4 a = ((const float4*)s)[t * 2];
  const float4 b = ((const float4*)s)[t * 2 + 1];
  float v[8] = {a.x, a.y, a.z, a.w, b.x, b.y, b.z, b.w};

  float mx = v[0];
#pragma unroll
  for (int i = 1; i < 8; ++i) mx = fmaxf(mx, v[i]);
#pragma unroll
  for (int off = 32; off > 0; off >>= 1) mx = fmaxf(mx, __shfl_xor(mx, off, 64));

  __shared__ float redm[4], reds[4];
  if ((t & 63) == 0) redm[t >> 6] = mx;
  __syncthreads();
  mx = fmaxf(fmaxf(redm[0], redm[1]), fmaxf(redm[2], redm[3]));

  float sum = 0.0f;
#pragma unroll
  for (int i = 0; i < 8; ++i) { v[i] = __expf(v[i] - mx); sum += v[i]; }
#pragma unroll
  for (int off = 32; off > 0; off >>= 1) sum += __shfl_xor(sum, off, 64);
  if ((t & 63) == 0) reds[t >> 6] = sum;
  __syncthreads();
  sum = reds[0] + reds[1] + reds[2] + reds[3];

  const float inv = 1.0f / sum;
  f16x8 h;
#pragma unroll
  for (int i = 0; i < 8; ++i) h[i] = (_Float16)(v[i] * inv);
  *(f16x8*)((ushort_t*)P + row * 2048 + t * 8) = h;
}

// ---------------------------------------------------------------------------
extern "C" void kernel_launch(void* const* d_in, const int* in_sizes, int n_in,
                              void* d_out, int out_size, void* d_ws, size_t ws_size,
                              hipStream_t stream)
{
  const int  Bb = 4, Nn = 2048, Dd = 1024;
  const long BN = (long)Bb * Nn;  // 8192

  const float* X  = (const float*)d_in[0];
  const float* Wq = (const float*)d_in[1];
  const float* bq = (const float*)d_in[2];
  const float* Wk = (const float*)d_in[3];
  const float* bk = (const float*)d_in[4];
  const float* Wv = (const float*)d_in[5];
  const float* bv = (const float*)d_in[6];
  float* Out      = (float*)d_out;

  uint8_t* w = (uint8_t*)d_ws;
  ushort_t* Wt = (ushort_t*)w;  w += (size_t)3 * Dd * Dd * 2;  // Wq^T|Wk^T|Wv^T fp16

  // Wt[z][e][k] = W[k][e], fp32 -> fp16 (one batched dispatch)
  transpose_cvt3_kernel<<<dim3(Dd / 32, Dd / 32, 3), 256, 0, stream>>>(Wq, Wk, Wv, (__half*)Wt);

  const size_t fullNeed = (size_t)3 * Dd * Dd * 2      // Wt
                        + 4 * ((size_t)BN * Dd * 2)    // Xh, Q, K, Vt fp16
                        + (size_t)Bb * Nn * Nn * 4     // S fp32
                        + (size_t)Bb * Nn * Nn * 2;    // P fp16

  if (ws_size >= fullNeed) {
    ushort_t* Xh = (ushort_t*)w;  w += (size_t)BN * Dd * 2;
    ushort_t* Q  = (ushort_t*)w;  w += (size_t)BN * Dd * 2;
    ushort_t* Kb = (ushort_t*)w;  w += (size_t)BN * Dd * 2;
    ushort_t* Vt = (ushort_t*)w;  w += (size_t)BN * Dd * 2;  // [B][Dd][Nn]
    float*    S  = (float*)w;     w += (size_t)Bb * Nn * Nn * 4;
    ushort_t* P  = (ushort_t*)w;

    // X -> fp16
    cvt_f32_f16_kernel<<<dim3((unsigned)(BN * Dd / (8 * 256))), 256, 0, stream>>>(
        X, (__half*)Xh, BN * Dd);

    // Fused QKV: [8192,1024] x [3072,1024]^T (+bias); V written transposed
    qkv_gemm_kernel<<<dim3(3 * Dd / 128, BN / 128, 1), 256, 0, stream>>>(
        Xh, Wt, bq, bk, bv, (__half*)Q, (__half*)Kb, Vt);

    // S[b] = Q[b] K[b]^T  (fp32)
    gemm_bt_kernel<float><<<dim3(Nn / 128, Nn / 128, Bb), 256, 0, stream>>>(
        Q, Kb, S, Nn, Dd, (long)Nn * Dd, (long)Nn * Dd, (long)Nn * Nn);

    // P = softmax(S) rows -> fp16
    softmax2048_kernel<<<dim3((unsigned)(Bb * (long)Nn)), 256, 0, stream>>>(S, (__half*)P);

    // O[b] = P[b] V[b] via Vt -> fp32 out
    gemm_bt_kernel<float><<<dim3(Dd / 128, Nn / 128, Bb), 256, 0, stream>>>(
        P, Vt, Out, Dd, Nn, (long)Nn * Nn, (long)Dd * Nn, (long)Nn * Dd);
  } else {
    // Per-batch fallback (~48 MB ws)
    ushort_t* Xh = (ushort_t*)w;  w += (size_t)Nn * Dd * 2;
    ushort_t* Q  = (ushort_t*)w;  w += (size_t)Nn * Dd * 2;
    ushort_t* Kb = (ushort_t*)w;  w += (size_t)Nn * Dd * 2;
    ushort_t* Vt = (ushort_t*)w;  w += (size_t)Nn * Dd * 2;
    float*    S  = (float*)w;     w += (size_t)Nn * Nn * 4;
    ushort_t* P  = (ushort_t*)w;

    for (int b = 0; b < Bb; ++b) {
      const float* Xb = X + (long)b * Nn * Dd;
      cvt_f32_f16_kernel<<<dim3((unsigned)((long)Nn * Dd / (8 * 256))), 256, 0, stream>>>(
          Xb, (__half*)Xh, (long)Nn * Dd);
      qkv_gemm_kernel<<<dim3(3 * Dd / 128, Nn / 128, 1), 256, 0, stream>>>(
          Xh, Wt, bq, bk, bv, (__half*)Q, (__half*)Kb, Vt);
      gemm_bt_kernel<float><<<dim3(Nn / 128, Nn / 128, 1), 256, 0, stream>>>(
          Q, Kb, S, Nn, Dd, 0, 0, 0);
      softmax2048_kernel<<<dim3(Nn), 256, 0, stream>>>(S, (__half*)P);
      gemm_bt_kernel<float><<<dim3(Dd / 128, Nn / 128, 1), 256, 0, stream>>>(
          P, Vt, Out + (long)b * Nn * Dd, Dd, Nn, 0, 0, 0);
    }
  }
}